// Round 1
// 442.557 us; speedup vs baseline: 1.0315x; 1.0315x over previous
//
#include <hip/hip_runtime.h>

// Fused tanh-RNN: h_{t+1} = tanh(x_t @ W_ih^T + b_ih + b_hh + h_t @ W_hh^T)
// out = h_T @ W_out^T + b_out.  B=4096, T=512, I=28, H=64, O=10.
//
// R5: PRE-SPLIT BF16 h-EXCHANGE. R4 (238 us dispatch) exchanged h as f32 and
// paid 48 dependent VALU ops (2x split8v) AFTER every barrier, right behind the
// lgkm wait -- the worst possible place on a serial chain. Now the producer
// splits tanh(h) to bf16 hi/lo (16 VALU + 8 ds_write_b16, overlappable with the
// tanh tail) and the consumer's 4 ds_read_b128 land DIRECTLY in MFMA A-frags:
// zero post-barrier VALU. The next step's x-split (independent) hides the read
// latency. MFMA reassociated into 3 accumulator chains: h-depth 3 -> 2.
// x prefetch uses rolling base pointers + compile-time byte offsets (no per-step
// 64-bit mul / clamp / cndmask; tail group is prefetch-free instead).
// Arithmetic is bit-identical to R4 (same truncation split, same MFMA terms):
// absmax stays ~0.0039 vs threshold 0.0255.
//
// LDS layout (per buffer, double-buffered): bf16 [row=batch 16][k=hidden], row
// stride 72 elements = 144 B = 9 bfrags -> lane (c,q) reads 16B at 144c+16q:
// every aligned 16-lane phase tiles the 32 banks exactly twice (the structural
// minimum for a 1KB wave read). hi rows at [0,1152) elements, lo at [1152,2304).

#define T_STEPS 512
#define I_DIM   28
#define H_DIM   64
#define O_DIM   10
#define ROWS    16

#define RS_EL   72            // row stride, bf16 elements (64 + 8 pad)
#define LO_EL   1152          // 16*72: lo-array offset, elements
#define LO_FR   144           // same, in bfrag(16B) units
#define BUF_EL  2304          // elements per buffer (hi+lo)
#define BUF_FR  288

typedef __attribute__((ext_vector_type(8))) short bfrag;   // 8 x bf16 (4 VGPRs)
typedef __attribute__((ext_vector_type(4))) float ffrag;   // MFMA C/D
typedef __attribute__((ext_vector_type(4))) float float4v;

#define MFMA(a,b,c) __builtin_amdgcn_mfma_f32_16x16x32_bf16((a),(b),(c),0,0,0)
// Workgroup barrier draining ONLY LDS ops (lgkmcnt). Inter-wave deps are
// LDS-only; the x register prefetch (vmcnt) legally stays in flight across it.
#define LDS_BARRIER() asm volatile("s_waitcnt lgkmcnt(0)\n\ts_barrier" ::: "memory")

union FragU { bfrag s; unsigned u[4]; };

// pack bf16(f0) | bf16(f1)<<16 in one v_perm_b32 (truncation split)
__device__ __forceinline__ unsigned hi_pack(float f0, float f1){
  return __builtin_amdgcn_perm(__float_as_uint(f1), __float_as_uint(f0), 0x07060302u);
}

// fp32 -> (hi bf16, lo bf16), v = hi + lo up to ~2^-16 rel
__device__ __forceinline__ void split8v(float4v a, float4v b, bfrag& hi, bfrag& lo){
  float f[8] = {a.x,a.y,a.z,a.w, b.x,b.y,b.z,b.w};
  FragU H, L;
#pragma unroll
  for (int m = 0; m < 4; m++){
    float f0 = f[2*m], f1 = f[2*m+1];
    H.u[m] = hi_pack(f0, f1);
    float l0 = f0 - __uint_as_float(__float_as_uint(f0) & 0xffff0000u);
    float l1 = f1 - __uint_as_float(__float_as_uint(f1) & 0xffff0000u);
    L.u[m] = hi_pack(l0, l1);
  }
  hi = H.s; lo = L.s;
}

__device__ __forceinline__ float fast_tanh(float p){
  // tanh(p) = 1 - 2/(exp2(2*log2e*p)+1); saturates correctly for large |p|.
  float e = __builtin_amdgcn_exp2f(p * 2.88539008177792681f);
  return __builtin_fmaf(-2.0f, __builtin_amdgcn_rcpf(e + 1.0f), 1.0f);
}

// One RNN step for one wave (its 16 hidden cols). Slot K's x regs are consumed,
// then (PF) overwritten with the t+4 row at a compile-time byte offset.
// WP: bf16 write base (this step's h buffer), RP: bfrag read base (same buffer).
#define BODY(K, WP, RP, PF)                                                    \
  {                                                                            \
    bfrag xhi, xlo;                                                            \
    split8v(xa[K], xb[K], xhi, xlo);                                           \
    if (PF){                                                                   \
      xa[K] = *(const float4v*)(xpa + ((K) + 4) * I_DIM);                      \
      xb[K] = *(const float4v*)(xpb + ((K) + 4) * I_DIM);                      \
    }                                                                          \
    ffrag P, Q, R;                                                             \
    /* x projection heads the chains (x ready 4 steps early) */                \
    P = MFMA(xhi, wih_hi, biasf);                                              \
    Q = MFMA(xhi, wih_lo, zfrag);                                              \
    P = MFMA(xlo, wih_hi, P);                                                  \
    /* h recurrence: 3 chains, depth 2 from h-ready */                         \
    P = MFMA(h_hi[0], whh_hi[0], P);                                           \
    Q = MFMA(h_hi[1], whh_hi[1], Q);                                           \
    R = MFMA(h_hi[0], whh_lo[0], zfrag);                                       \
    P = MFMA(h_lo[0], whh_hi[0], P);                                           \
    Q = MFMA(h_lo[1], whh_hi[1], Q);                                           \
    R = MFMA(h_hi[1], whh_lo[1], R);                                           \
    float fs[4];                                                               \
    fs[0] = (P.x + Q.x) + R.x;                                                 \
    fs[1] = (P.y + Q.y) + R.y;                                                 \
    fs[2] = (P.z + Q.z) + R.z;                                                 \
    fs[3] = (P.w + Q.w) + R.w;                                                 \
    /* tanh -> producer-side truncation split -> b16 stores (rows 4q+m) */     \
    _Pragma("unroll")                                                          \
    for (int m = 0; m < 4; ++m){                                               \
      float f = fast_tanh(fs[m]);                                              \
      unsigned u = __float_as_uint(f);                                         \
      (WP)[m*RS_EL] = (unsigned short)(u >> 16);                               \
      float l = f - __uint_as_float(u & 0xffff0000u);                          \
      (WP)[m*RS_EL + LO_EL] = (unsigned short)(__float_as_uint(l) >> 16);      \
    }                                                                          \
    LDS_BARRIER();                                                             \
    /* reload FULL h(t+1): 4 ds_read_b128, zero VALU -- frags land directly */ \
    h_hi[0] = (RP)[0];                                                         \
    h_hi[1] = (RP)[4];                                                         \
    h_lo[0] = (RP)[LO_FR];                                                     \
    h_lo[1] = (RP)[LO_FR + 4];                                                 \
  }

__global__ __launch_bounds__(256, 1) void rnn_fused(
    const float* __restrict__ x,
    const float* __restrict__ W_ih,
    const float* __restrict__ W_hh,
    const float* __restrict__ b_ih,
    const float* __restrict__ b_hh,
    const float* __restrict__ W_out,
    const float* __restrict__ b_out,
    float* __restrict__ out)
{
  __shared__ bfrag hsv[2 * BUF_FR];            // 9216 B, double-buffered bf16 h
  const int tid  = threadIdx.x;
  const int w    = tid >> 6;           // wave id = hidden col tile
  const int lane = tid & 63;
  const int c    = lane & 15;
  const int q    = lane >> 4;
  const bool qlt3 = (q < 3);
  const int rowbase = blockIdx.x * ROWS;

  // ---- this wave's W_hh^T B-fragments (hi/lo): cols c+16w, k=32kt+8q+jj ----
  bfrag whh_hi[2], whh_lo[2];
#pragma unroll
  for (int kt = 0; kt < 2; ++kt){
    const float* p = W_hh + (c + 16*w)*H_DIM + kt*32 + q*8;
    split8v(*(const float4v*)p, *(const float4v*)(p + 4), whh_hi[kt], whh_lo[kt]);
  }

  // ---- this wave's W_ih^T B-fragment, K padded 28 -> 32 with zeros ----
  bfrag wih_hi, wih_lo;
  {
    const float* p = W_ih + (c + 16*w)*I_DIM + q*8;
    float4v a = *(const float4v*)p;                        // i <= 27: in-bounds
    float4v b;
    if (qlt3) b = *(const float4v*)(p + 4);
    else      b = (float4v){0.f, 0.f, 0.f, 0.f};           // i = 28..31 pad
    split8v(a, b, wih_hi, wih_lo);
  }

  // bias as C operand; const-zero C for the other chains
  ffrag biasf;
  {
    float bb = b_ih[c + 16*w] + b_hh[c + 16*w];
    biasf.x = bb; biasf.y = bb; biasf.z = bb; biasf.w = bb;
  }
  const ffrag zfrag = {0.f, 0.f, 0.f, 0.f};

  // h fragments (full h as A operand), h0 = 0
  bfrag h_hi[2], h_lo[2];
  {
    FragU Z; Z.u[0]=Z.u[1]=Z.u[2]=Z.u[3]=0;
    h_hi[0] = Z.s; h_lo[0] = Z.s; h_hi[1] = Z.s; h_lo[1] = Z.s;
  }

  // LDS addressing, all precomputed (ds offsets become immediates):
  // producer writes row=4q+m, col=c+16w; consumer reads row=c, k=32kt+8q+jj.
  unsigned short* const wbase = (unsigned short*)hsv;
  unsigned short* const wp0 = wbase + 0*BUF_EL + (4*q)*RS_EL + (c + 16*w);
  unsigned short* const wp1 = wbase + 1*BUF_EL + (4*q)*RS_EL + (c + 16*w);
  const bfrag* const rp0 = hsv + 0*BUF_FR + 9*c + q;
  const bfrag* const rp1 = hsv + 1*BUF_FR + 9*c + q;

  // ---- 4-slot x pipeline (all 4 waves load the same rows; L1 dedupes).
  // A-frag: row r=c, i=q*8+jj; quad 3's upper float4 multiplies zero W pad ->
  // point it back at lp (in-bounds, value don't-care), hoisted into xpb.
  const float* xpa = x + ((size_t)(rowbase + c) * T_STEPS) * I_DIM + q*8;
  const float* xpb = qlt3 ? xpa + 4 : xpa;
  float4v xa[4], xb[4];
#pragma unroll
  for (int s = 0; s < 4; ++s){
    xa[s] = *(const float4v*)(xpa + s * I_DIM);
    xb[s] = *(const float4v*)(xpb + s * I_DIM);
  }

  // main: 127 groups with prefetch (last prefetches t=508..511), then a
  // prefetch-free tail group. Even t writes buffer 1, odd t buffer 0.
#pragma unroll 1
  for (int tb = 0; tb < T_STEPS - 4; tb += 4){
    BODY(0, wp1, rp1, 1)
    BODY(1, wp0, rp0, 1)
    BODY(2, wp1, rp1, 1)
    BODY(3, wp0, rp0, 1)
    xpa += 4 * I_DIM;
    xpb += 4 * I_DIM;
  }
  BODY(0, wp1, rp1, 0)
  BODY(1, wp0, rp0, 0)
  BODY(2, wp1, rp1, 0)
  BODY(3, wp0, rp0, 0)

  // epilogue: h_512 is in buffer 0 (t=511 wrote buffer 0). wave 0 computes
  // out[r][o] = b_out[o] + sum_k (hi+lo)[r][k] * W_out[o][k], r=c, o strided q.
  if (w == 0){
    const unsigned short* hb = (const unsigned short*)hsv;   // buffer 0
    for (int oo = q; oo < O_DIM; oo += 4){
      float s = b_out[oo];
#pragma unroll 8
      for (int k = 0; k < H_DIM; ++k){
        float hv = __uint_as_float((unsigned)hb[c*RS_EL + k] << 16)
                 + __uint_as_float((unsigned)hb[c*RS_EL + k + LO_EL] << 16);
        s += hv * W_out[oo*H_DIM + k];
      }
      out[(size_t)(rowbase + c)*O_DIM + oo] = s;
    }
  }
}

extern "C" void kernel_launch(void* const* d_in, const int* in_sizes, int n_in,
                              void* d_out, int out_size, void* d_ws, size_t ws_size,
                              hipStream_t stream) {
  const float* x     = (const float*)d_in[0];
  const float* W_ih  = (const float*)d_in[1];
  const float* W_hh  = (const float*)d_in[2];
  const float* b_ih  = (const float*)d_in[3];
  const float* b_hh  = (const float*)d_in[4];
  const float* W_out = (const float*)d_in[5];
  const float* b_out = (const float*)d_in[6];
  float* out = (float*)d_out;

  int B = in_sizes[0] / (T_STEPS * I_DIM);   // 4096
  rnn_fused<<<B / ROWS, 256, 0, stream>>>(x, W_ih, W_hh, b_ih, b_hh, W_out, b_out, out);
}